// Round 8
// baseline (646.623 us; speedup 1.0000x reference)
//
#include <hip/hip_runtime.h>
#include <math.h>

#define H_HEADS 33
#define C_CH    16
#define HC      528      // H_HEADS * C_CH
#define F_IN    128
#define NEG_SLOPE 0.2f

typedef short  bf16x8  __attribute__((ext_vector_type(8)));
typedef float  floatx4 __attribute__((ext_vector_type(4)));

__device__ inline unsigned short f2bf(float f) {   // RNE float->bf16
    unsigned int u = __float_as_uint(f);
    unsigned int r = u + 0x7fffu + ((u >> 16) & 1u);
    return (unsigned short)(r >> 16);
}
__device__ inline float bf2f(unsigned short u) {
    return __uint_as_float((unsigned int)u << 16);
}

// ---------------------------------------------------------------------------
// K0a: xb = bf16(x)
// ---------------------------------------------------------------------------
__global__ void cvt_x_kernel(const float* __restrict__ x,
                             unsigned short* __restrict__ xb, int total4)
{
    int g = blockIdx.x * blockDim.x + threadIdx.x;
    if (g >= total4) return;
    float4 v = ((const float4*)x)[g];
    unsigned int lo = (unsigned int)f2bf(v.x) | ((unsigned int)f2bf(v.y) << 16);
    unsigned int hi = (unsigned int)f2bf(v.z) | ((unsigned int)f2bf(v.w) << 16);
    ((uint2*)xb)[g] = make_uint2(lo, hi);
}

// K0b: Wt = bf16(W^T), [528][128]
__global__ void cvt_w_kernel(const float* __restrict__ W,
                             unsigned short* __restrict__ Wt)
{
    int g = blockIdx.x * blockDim.x + threadIdx.x;
    if (g >= F_IN * HC) return;
    int k = g / HC, n = g % HC;
    Wt[n * F_IN + k] = f2bf(W[g]);
}

// ---------------------------------------------------------------------------
// Dual histogram: cnt_s[src]++, cnt_d[dst]++ (self loops appended).
// ---------------------------------------------------------------------------
__global__ void hist_kernel(const int* __restrict__ ei,
                            int* __restrict__ cnt_s, int* __restrict__ cnt_d,
                            int E, int Et)
{
    int g = blockIdx.x * blockDim.x + threadIdx.x;
    if (g >= Et) return;
    int src, dst;
    if (g < E) { src = ei[g]; dst = ei[E + g]; }
    else       { src = dst = g - E; }
    atomicAdd(&cnt_s[src], 1);
    atomicAdd(&cnt_d[dst], 1);
}

__global__ __launch_bounds__(256) void scan_block_kernel(
    const int* __restrict__ cnt, int* __restrict__ ex,
    int* __restrict__ bsum, int N)
{
    __shared__ int s[256];
    const int t = threadIdx.x;
    const int base = blockIdx.x * 1024 + t * 4;
    int c[4], tot = 0;
    #pragma unroll
    for (int j = 0; j < 4; ++j) {
        c[j] = (base + j < N) ? cnt[base + j] : 0;
        tot += c[j];
    }
    s[t] = tot;
    __syncthreads();
    #pragma unroll
    for (int off = 1; off < 256; off <<= 1) {
        int v = (t >= off) ? s[t - off] : 0;
        __syncthreads();
        s[t] += v;
        __syncthreads();
    }
    if (t == 255) bsum[blockIdx.x] = s[255];
    int run = s[t] - tot;
    #pragma unroll
    for (int j = 0; j < 4; ++j) {
        if (base + j < N) ex[base + j] = run;
        run += c[j];
    }
}

// block 0: bsum_s, block 1: bsum_d (nb <= 64 each)
__global__ void scan_bsum_kernel(int* __restrict__ bsum_s,
                                 int* __restrict__ bsum_d, int nb)
{
    int* bsum = (blockIdx.x == 0) ? bsum_s : bsum_d;
    int lane = threadIdx.x;
    int v = (lane < nb) ? bsum[lane] : 0;
    int inc = v;
    #pragma unroll
    for (int off = 1; off < 64; off <<= 1) {
        int u = __shfl_up(inc, off);
        if (lane >= off) inc += u;
    }
    if (lane < nb) bsum[lane] = inc - v;
}

// rowptr[i] = bsum_d[i>>10] + ex_d[i]  (before scatter mutates ex_d)
__global__ void rowptr_kernel(const int* __restrict__ ex_d,
                              const int* __restrict__ bsum_d,
                              int* __restrict__ rowptr, int N, int Et)
{
    int g = blockIdx.x * blockDim.x + threadIdx.x;
    if (g > N) return;
    rowptr[g] = (g < N) ? bsum_d[g >> 10] + ex_d[g] : Et;
}

// scatter into src-sorted perm_s AND dst-sorted sd (src value per slot)
__global__ void scatter_kernel(const int* __restrict__ ei,
                               const int* __restrict__ bsum_s, int* __restrict__ ex_s,
                               int* __restrict__ perm_s,
                               const int* __restrict__ bsum_d, int* __restrict__ ex_d,
                               int* __restrict__ sd,
                               int E, int Et)
{
    int g = blockIdx.x * blockDim.x + threadIdx.x;
    if (g >= Et) return;
    int src, dst;
    if (g < E) { src = ei[g]; dst = ei[E + g]; }
    else       { src = dst = g - E; }
    int ps = bsum_s[src >> 10] + atomicAdd(&ex_s[src], 1);
    perm_s[ps] = g;
    int pd = bsum_d[dst >> 10] + atomicAdd(&ex_d[dst], 1);
    sd[pd] = src;
}

// ---------------------------------------------------------------------------
// K1: hb[N][528] row-layout = bf16(xb @ Wt^T), MFMA 16x16x32 bf16.
// BM=32, 6 waves; loop over 11 Wt strips (Wt 135KB = L2-resident, re-staged
// per block). Results go to a 33KB LDS row buffer; block writes 32 FULL
// contiguous 1056B rows -> full-line writes AND gather-friendly row layout.
// Wave w: m-tile = w&1, head-subtile = w>>1. a_srcT/a_dstT [33][N] fused.
// ---------------------------------------------------------------------------
#define LDA 136
__global__ __launch_bounds__(384) void gemm_att_kernel(
    const unsigned short* __restrict__ xb, const unsigned short* __restrict__ Wt,
    const float* __restrict__ att_src, const float* __restrict__ att_dst,
    unsigned short* __restrict__ hb,
    float* __restrict__ a_srcT, float* __restrict__ a_dstT, int N)
{
    __shared__ unsigned short As[32][LDA];    // 8.7 KB
    __shared__ unsigned short Bs[48][LDA];    // 13.1 KB
    __shared__ unsigned short buf[32][528];   // 33.8 KB

    const int tid  = threadIdx.x;
    const int lane = tid & 63;
    const int wave = tid >> 6;      // 0..5
    const int mt   = wave & 1;      // m-tile 0/1
    const int st   = wave >> 1;     // head-subtile 0..2
    const int lm   = lane & 15;
    const int kc   = lane >> 4;
    const int m0   = blockIdx.x * 32;

    // stage As: 32 rows x 16 uint4 (256B/row)
    for (int e = tid; e < 32 * 16; e += 384) {
        int r = e >> 4, c = e & 15;
        int gr = m0 + r;
        uint4 v = (gr < N) ? ((const uint4*)(xb + (size_t)gr * F_IN))[c]
                           : make_uint4(0, 0, 0, 0);
        *(uint4*)&As[r][c * 8] = v;
    }

    for (int y = 0; y < 11; ++y) {
        __syncthreads();           // Bs from prev strip fully consumed
        for (int e = tid; e < 48 * 16; e += 384) {
            int r = e >> 4, c = e & 15;
            uint4 v = ((const uint4*)(Wt + (size_t)(y * 48 + r) * F_IN))[c];
            *(uint4*)&Bs[r][c * 8] = v;
        }
        __syncthreads();           // also covers As on first iteration

        floatx4 acc = {};
        const int arow = mt * 16 + lm;
        #pragma unroll
        for (int ks = 0; ks < 4; ++ks) {
            bf16x8 a = *(const bf16x8*)&As[arow][ks * 32 + kc * 8];
            bf16x8 b = *(const bf16x8*)&Bs[st * 16 + lm][ks * 32 + kc * 8];
            acc = __builtin_amdgcn_mfma_f32_16x16x32_bf16(a, b, acc, 0, 0, 0);
        }

        // C/D layout: col = lane&15, row = (lane>>4)*4 + reg
        const int head = y * 3 + st;
        const float w_s = att_src[head * C_CH + lm];
        const float w_d = att_dst[head * C_CH + lm];
        #pragma unroll
        for (int r = 0; r < 4; ++r) {
            const int row = mt * 16 + kc * 4 + r;   // 0..31 local
            float s = acc[r] * w_s;
            float d = acc[r] * w_d;
            #pragma unroll
            for (int m = 8; m >= 1; m >>= 1) {
                s += __shfl_xor(s, m);
                d += __shfl_xor(d, m);
            }
            buf[row][head * C_CH + lm] = f2bf(acc[r]);
            if (lm == 0 && m0 + row < N) {
                a_srcT[(size_t)head * N + m0 + row] = s;
                a_dstT[(size_t)head * N + m0 + row] = d;
            }
        }
    }
    __syncthreads();

    // write 32 full rows: 32 x 66 uint4, fully contiguous per block
    for (int e = tid; e < 32 * 66; e += 384) {
        int r = e / 66, c = e - r * 66;
        int gr = m0 + r;
        if (gr < N)
            ((uint4*)(hb + (size_t)gr * HC))[c] = *(uint4*)&buf[r][c * 8];
    }
}

// ---------------------------------------------------------------------------
// K2: dst-CSR denom — one thread per (head,dst) walks its contiguous edge
// run; gathers hit the L2-resident a_srcT plane; single coalesced store of
// 1/(sum+eps). No atomics. segment-max skipped (|e| small, shift-invariant).
// ---------------------------------------------------------------------------
__global__ void denom_kernel(const int* __restrict__ rowptr,
                             const int* __restrict__ sd,
                             const float* __restrict__ a_srcT,
                             const float* __restrict__ a_dstT,
                             float* __restrict__ inv_denomT, int N)
{
    int g = blockIdx.x * blockDim.x + threadIdx.x;
    if (g >= N * H_HEADS) return;
    int hd = g / N, dst = g - hd * N;
    const float* aS = a_srcT + (size_t)hd * N;
    const float ad = a_dstT[(size_t)hd * N + dst];
    const int jb = rowptr[dst], je = rowptr[dst + 1];
    float sum = 0.f;
    for (int j = jb; j < je; ++j) {
        float v = aS[sd[j]] + ad;
        v = v > 0.f ? v : NEG_SLOPE * v;
        sum += __expf(v);
    }
    inv_denomT[g] = 1.0f / (sum + 1e-16f);
}

// ---------------------------------------------------------------------------
// K3: 16 edges/block in src-sorted order (row-layout hb gathers cache-hot).
// Phase 1: 16x33 alphas once into LDS. Phase 2: lane (edge,c) gathers the
// contiguous 1056B h row, fma, 16-float atomic bundle per edge.
// ---------------------------------------------------------------------------
#define EPB 16
__global__ __launch_bounds__(256) void aggregate_kernel(
    const int* __restrict__ ei, const int* __restrict__ perm,
    const float* __restrict__ a_srcT, const float* __restrict__ a_dstT,
    const float* __restrict__ inv_denomT,
    const unsigned short* __restrict__ hb,
    float* __restrict__ out, int E, int Et, int N)
{
    __shared__ int   s_src[EPB], s_dst[EPB];
    __shared__ float s_alpha[EPB][H_HEADS];

    const int tid = threadIdx.x;
    const int e0  = blockIdx.x * EPB;

    if (tid < EPB) {
        int idx = e0 + tid;
        int s = 0, d = 0;
        if (idx < Et) {
            int e = perm[idx];
            if (e < E) { s = ei[e]; d = ei[E + e]; }
            else       { s = d = e - E; }
        }
        s_src[tid] = s;
        s_dst[tid] = d;
    }
    __syncthreads();

    for (int i = tid; i < EPB * H_HEADS; i += 256) {
        int hd = i >> 4, el = i & 15;          // EPB == 16
        if (e0 + el < Et) {
            int src = s_src[el], dst = s_dst[el];
            float v = a_srcT[(size_t)hd * N + src] + a_dstT[(size_t)hd * N + dst];
            v = v > 0.f ? v : NEG_SLOPE * v;
            s_alpha[el][hd] = __expf(v) * inv_denomT[(size_t)hd * N + dst];
        }
    }
    __syncthreads();

    const int el = tid >> 4, c = tid & 15;
    if (e0 + el >= Et) return;
    const int src = s_src[el], dst = s_dst[el];
    const unsigned short* hs = hb + (size_t)src * HC + c;
    float acc = 0.f;
    #pragma unroll
    for (int hd = 0; hd < H_HEADS; ++hd)
        acc += s_alpha[el][hd] * bf2f(hs[hd * C_CH]);
    atomicAdd(&out[dst * C_CH + c], acc);
}

// K4: out = tanh(out/H + bias), in place
__global__ void finalize_kernel(float* __restrict__ out,
                                const float* __restrict__ bias, int total)
{
    int g = blockIdx.x * blockDim.x + threadIdx.x;
    if (g >= total) return;
    out[g] = tanhf(out[g] * (1.0f / 33.0f) + bias[g & 15]);
}

// ---------------------------------------------------------------------------
extern "C" void kernel_launch(void* const* d_in, const int* in_sizes, int n_in,
                              void* d_out, int out_size, void* d_ws, size_t ws_size,
                              hipStream_t stream)
{
    const float* x       = (const float*)d_in[0];
    const int*   ei      = (const int*)  d_in[1];
    const float* W       = (const float*)d_in[2];
    const float* att_src = (const float*)d_in[3];
    const float* att_dst = (const float*)d_in[4];
    const float* bias    = (const float*)d_in[5];
    float* out = (float*)d_out;

    const int N  = in_sizes[0] / F_IN;   // 50000
    const int E  = in_sizes[1] / 2;      // 320000
    const int Et = E + N;                // with self loops
    const int NB = (N + 1023) / 1024;    // scan blocks (49)

    // workspace layout
    unsigned short* hb = (unsigned short*)d_ws;                    // [N][528]
    float* a_srcT = (float*)(hb + (size_t)N * HC);                 // [33][N]
    float* a_dstT = a_srcT + (size_t)H_HEADS * N;
    float* invdT  = a_dstT + (size_t)H_HEADS * N;                  // [33][N]
    unsigned short* xb = (unsigned short*)(invdT + (size_t)H_HEADS * N);
    unsigned short* Wt = xb + (size_t)N * F_IN;
    int* cnt_s  = (int*)(Wt + (size_t)HC * F_IN);
    int* ex_s   = cnt_s + N;
    int* bsum_s = ex_s + N;               // 64
    int* perm_s = bsum_s + 64;            // Et
    int* cnt_d  = perm_s + Et;
    int* ex_d   = cnt_d + N;
    int* bsum_d = ex_d + N;               // 64
    int* rowptr = bsum_d + 64;            // N+1
    int* sd     = rowptr + N + 1;         // Et

    hipMemsetAsync(d_out, 0, (size_t)out_size * sizeof(float), stream);
    hipMemsetAsync(cnt_s, 0, (size_t)N * sizeof(int), stream);
    hipMemsetAsync(cnt_d, 0, (size_t)N * sizeof(int), stream);

    int total4 = N * F_IN / 4;
    cvt_x_kernel<<<(total4 + 255) / 256, 256, 0, stream>>>(x, xb, total4);
    cvt_w_kernel<<<(F_IN * HC + 255) / 256, 256, 0, stream>>>(W, Wt);

    hist_kernel<<<(Et + 255) / 256, 256, 0, stream>>>(ei, cnt_s, cnt_d, E, Et);
    scan_block_kernel<<<NB, 256, 0, stream>>>(cnt_s, ex_s, bsum_s, N);
    scan_block_kernel<<<NB, 256, 0, stream>>>(cnt_d, ex_d, bsum_d, N);
    scan_bsum_kernel<<<2, 64, 0, stream>>>(bsum_s, bsum_d, NB);
    rowptr_kernel<<<(N + 256) / 256, 256, 0, stream>>>(ex_d, bsum_d, rowptr, N, Et);
    scatter_kernel<<<(Et + 255) / 256, 256, 0, stream>>>(
        ei, bsum_s, ex_s, perm_s, bsum_d, ex_d, sd, E, Et);

    gemm_att_kernel<<<(N + 31) / 32, 384, 0, stream>>>(xb, Wt, att_src, att_dst,
                                                       hb, a_srcT, a_dstT, N);

    int totA = N * H_HEADS;
    denom_kernel<<<(totA + 255) / 256, 256, 0, stream>>>(rowptr, sd, a_srcT,
                                                         a_dstT, invdT, N);

    aggregate_kernel<<<(Et + EPB - 1) / EPB, 256, 0, stream>>>(
        ei, perm_s, a_srcT, a_dstT, invdT, hb, out, E, Et, N);

    int totO = N * C_CH;
    finalize_kernel<<<(totO + 255) / 256, 256, 0, stream>>>(out, bias, totO);
}

// Round 9
// 373.296 us; speedup vs baseline: 1.7322x; 1.7322x over previous
//
#include <hip/hip_runtime.h>
#include <math.h>

#define H_HEADS 33
#define C_CH    16
#define HC      528      // H_HEADS * C_CH
#define F_IN    128
#define NEG_SLOPE 0.2f

typedef short  bf16x8  __attribute__((ext_vector_type(8)));
typedef float  floatx4 __attribute__((ext_vector_type(4)));

__device__ inline unsigned short f2bf(float f) {   // RNE float->bf16
    unsigned int u = __float_as_uint(f);
    unsigned int r = u + 0x7fffu + ((u >> 16) & 1u);
    return (unsigned short)(r >> 16);
}
__device__ inline float bf2f(unsigned short u) {
    return __uint_as_float((unsigned int)u << 16);
}

// ---------------------------------------------------------------------------
// K0a: xb = bf16(x)
// ---------------------------------------------------------------------------
__global__ void cvt_x_kernel(const float* __restrict__ x,
                             unsigned short* __restrict__ xb, int total4)
{
    int g = blockIdx.x * blockDim.x + threadIdx.x;
    if (g >= total4) return;
    float4 v = ((const float4*)x)[g];
    unsigned int lo = (unsigned int)f2bf(v.x) | ((unsigned int)f2bf(v.y) << 16);
    unsigned int hi = (unsigned int)f2bf(v.z) | ((unsigned int)f2bf(v.w) << 16);
    ((uint2*)xb)[g] = make_uint2(lo, hi);
}

// K0b: Wt = bf16(W^T), [528][128]
__global__ void cvt_w_kernel(const float* __restrict__ W,
                             unsigned short* __restrict__ Wt)
{
    int g = blockIdx.x * blockDim.x + threadIdx.x;
    if (g >= F_IN * HC) return;
    int k = g / HC, n = g % HC;
    Wt[n * F_IN + k] = f2bf(W[g]);
}

// ---------------------------------------------------------------------------
// Dual histogram: cnt_s[src]++, cnt_d[dst]++ (self loops appended).
// ---------------------------------------------------------------------------
__global__ void hist_kernel(const int* __restrict__ ei,
                            int* __restrict__ cnt_s, int* __restrict__ cnt_d,
                            int E, int Et)
{
    int g = blockIdx.x * blockDim.x + threadIdx.x;
    if (g >= Et) return;
    int src, dst;
    if (g < E) { src = ei[g]; dst = ei[E + g]; }
    else       { src = dst = g - E; }
    atomicAdd(&cnt_s[src], 1);
    atomicAdd(&cnt_d[dst], 1);
}

__global__ __launch_bounds__(256) void scan_block_kernel(
    const int* __restrict__ cnt, int* __restrict__ ex,
    int* __restrict__ bsum, int N)
{
    __shared__ int s[256];
    const int t = threadIdx.x;
    const int base = blockIdx.x * 1024 + t * 4;
    int c[4], tot = 0;
    #pragma unroll
    for (int j = 0; j < 4; ++j) {
        c[j] = (base + j < N) ? cnt[base + j] : 0;
        tot += c[j];
    }
    s[t] = tot;
    __syncthreads();
    #pragma unroll
    for (int off = 1; off < 256; off <<= 1) {
        int v = (t >= off) ? s[t - off] : 0;
        __syncthreads();
        s[t] += v;
        __syncthreads();
    }
    if (t == 255) bsum[blockIdx.x] = s[255];
    int run = s[t] - tot;
    #pragma unroll
    for (int j = 0; j < 4; ++j) {
        if (base + j < N) ex[base + j] = run;
        run += c[j];
    }
}

// block 0: bsum_s, block 1: bsum_d (nb <= 64 each)
__global__ void scan_bsum_kernel(int* __restrict__ bsum_s,
                                 int* __restrict__ bsum_d, int nb)
{
    int* bsum = (blockIdx.x == 0) ? bsum_s : bsum_d;
    int lane = threadIdx.x;
    int v = (lane < nb) ? bsum[lane] : 0;
    int inc = v;
    #pragma unroll
    for (int off = 1; off < 64; off <<= 1) {
        int u = __shfl_up(inc, off);
        if (lane >= off) inc += u;
    }
    if (lane < nb) bsum[lane] = inc - v;
}

// rowptr[i] = bsum_d[i>>10] + ex_d[i]  (before scatter mutates ex_d)
__global__ void rowptr_kernel(const int* __restrict__ ex_d,
                              const int* __restrict__ bsum_d,
                              int* __restrict__ rowptr, int N, int Et)
{
    int g = blockIdx.x * blockDim.x + threadIdx.x;
    if (g > N) return;
    rowptr[g] = (g < N) ? bsum_d[g >> 10] + ex_d[g] : Et;
}

// scatter into src-sorted perm_s AND dst-sorted sd (src value per slot)
__global__ void scatter_kernel(const int* __restrict__ ei,
                               const int* __restrict__ bsum_s, int* __restrict__ ex_s,
                               int* __restrict__ perm_s,
                               const int* __restrict__ bsum_d, int* __restrict__ ex_d,
                               int* __restrict__ sd,
                               int E, int Et)
{
    int g = blockIdx.x * blockDim.x + threadIdx.x;
    if (g >= Et) return;
    int src, dst;
    if (g < E) { src = ei[g]; dst = ei[E + g]; }
    else       { src = dst = g - E; }
    int ps = bsum_s[src >> 10] + atomicAdd(&ex_s[src], 1);
    perm_s[ps] = g;
    int pd = bsum_d[dst >> 10] + atomicAdd(&ex_d[dst], 1);
    sd[pd] = src;
}

// ---------------------------------------------------------------------------
// K1: hb[N][528] = bf16(xb @ Wt^T), MFMA 16x16x32 bf16. BM=64, 4 waves,
// FULL 528-wide output in 33 acc quads per lane; loop over 11 L2-resident
// Wt strips. Epilogue writes complete contiguous h rows from registers
// (full-line coverage) + aR/dR in [N][33] (block covers the whole
// [m0*33,(m0+64)*33) region -> full-line coverage, no RMW).
// ---------------------------------------------------------------------------
#define LDA 136
__global__ __launch_bounds__(256) void gemm_att_kernel(
    const unsigned short* __restrict__ xb, const unsigned short* __restrict__ Wt,
    const float* __restrict__ att_src, const float* __restrict__ att_dst,
    unsigned short* __restrict__ hb,
    float* __restrict__ aR, float* __restrict__ dR, int N)
{
    __shared__ unsigned short As[64][LDA];    // 17.4 KB
    __shared__ unsigned short Bs[48][LDA];    // 13.1 KB

    const int tid  = threadIdx.x;
    const int lane = tid & 63;
    const int wave = tid >> 6;      // 0..3 -> m-tile
    const int lm   = lane & 15;
    const int kc   = lane >> 4;
    const int m0   = blockIdx.x * 64;

    // stage As: 64 rows x 16 uint4 (256B/row)
    for (int e = tid; e < 64 * 16; e += 256) {
        int r = e >> 4, c = e & 15;
        int gr = m0 + r;
        uint4 v = (gr < N) ? ((const uint4*)(xb + (size_t)gr * F_IN))[c]
                           : make_uint4(0, 0, 0, 0);
        *(uint4*)&As[r][c * 8] = v;
    }

    floatx4 acc[33] = {};
    #pragma unroll
    for (int y = 0; y < 11; ++y) {
        __syncthreads();           // Bs consumed (y>0); As staged (y==0 needs 2nd)
        for (int e = tid; e < 48 * 16; e += 256) {
            int r = e >> 4, c = e & 15;
            uint4 v = ((const uint4*)(Wt + (size_t)(y * 48 + r) * F_IN))[c];
            *(uint4*)&Bs[r][c * 8] = v;
        }
        __syncthreads();

        #pragma unroll
        for (int ks = 0; ks < 4; ++ks) {
            bf16x8 a = *(const bf16x8*)&As[wave * 16 + lm][ks * 32 + kc * 8];
            #pragma unroll
            for (int t = 0; t < 3; ++t) {
                bf16x8 b = *(const bf16x8*)&Bs[t * 16 + lm][ks * 32 + kc * 8];
                acc[y * 3 + t] = __builtin_amdgcn_mfma_f32_16x16x32_bf16(
                    a, b, acc[y * 3 + t], 0, 0, 0);
            }
        }
    }

    // C/D layout: col = lane&15, row = (lane>>4)*4 + reg
    const int rbase = m0 + wave * 16 + kc * 4;
    #pragma unroll
    for (int h = 0; h < H_HEADS; ++h) {
        const float w_s = att_src[h * C_CH + lm];
        const float w_d = att_dst[h * C_CH + lm];
        #pragma unroll
        for (int r = 0; r < 4; ++r) {
            const int row = rbase + r;
            float v = acc[h][r];
            float s = v * w_s;
            float d = v * w_d;
            #pragma unroll
            for (int m = 8; m >= 1; m >>= 1) {
                s += __shfl_xor(s, m);
                d += __shfl_xor(d, m);
            }
            if (row < N) {
                hb[(size_t)row * HC + h * C_CH + lm] = f2bf(v);
                if (lm == 0) {
                    aR[row * H_HEADS + h] = s;
                    dR[row * H_HEADS + h] = d;
                }
            }
        }
    }
}

// ---------------------------------------------------------------------------
// K2: dst-CSR denom, dst-major threads: 33 consecutive lanes = one dst's 33
// heads, so each edge's gather aR[sd[j]*33+hd] is ONE 132B row shared by the
// group (line-coalesced), run length uniform within the group, coalesced
// 1/(sum+eps) store. No atomics. segment-max skipped (|e| small ->
// exp safe; softmax shift-invariant).
// ---------------------------------------------------------------------------
#define DPB 8   // dsts per block (blockDim = 8*33 = 264)
__global__ __launch_bounds__(264) void denom_kernel(
    const int* __restrict__ rowptr, const int* __restrict__ sd,
    const float* __restrict__ aR, const float* __restrict__ dR,
    float* __restrict__ iR, int N)
{
    const int t  = threadIdx.x;
    const int dl = t / H_HEADS, hd = t - dl * H_HEADS;
    const int dst = blockIdx.x * DPB + dl;
    if (dst >= N) return;
    const float ad = dR[dst * H_HEADS + hd];
    const int jb = rowptr[dst], je = rowptr[dst + 1];
    float sum = 0.f;
    for (int j = jb; j < je; ++j) {
        float v = aR[sd[j] * H_HEADS + hd] + ad;
        v = v > 0.f ? v : NEG_SLOPE * v;
        sum += __expf(v);
    }
    iR[dst * H_HEADS + hd] = 1.0f / (sum + 1e-16f);
}

// ---------------------------------------------------------------------------
// K3: 16 edges/block in src-sorted order (row-layout hb gathers cache-hot).
// Phase 1: 16x33 alphas once into LDS ([N][33] reads: contiguous 132B/edge).
// Phase 2: lane (edge,c) gathers the contiguous 1056B h row, fma, 16-float
// atomic bundle per edge.
// ---------------------------------------------------------------------------
#define EPB 16
__global__ __launch_bounds__(256) void aggregate_kernel(
    const int* __restrict__ ei, const int* __restrict__ perm,
    const float* __restrict__ aR, const float* __restrict__ dR,
    const float* __restrict__ iR,
    const unsigned short* __restrict__ hb,
    float* __restrict__ out, int E, int Et, int N)
{
    __shared__ int   s_src[EPB], s_dst[EPB];
    __shared__ float s_alpha[EPB][H_HEADS];

    const int tid = threadIdx.x;
    const int e0  = blockIdx.x * EPB;

    if (tid < EPB) {
        int idx = e0 + tid;
        int s = 0, d = 0;
        if (idx < Et) {
            int e = perm[idx];
            if (e < E) { s = ei[e]; d = ei[E + e]; }
            else       { s = d = e - E; }
        }
        s_src[tid] = s;
        s_dst[tid] = d;
    }
    __syncthreads();

    for (int i = tid; i < EPB * H_HEADS; i += 256) {
        int el = i / H_HEADS, hd = i - el * H_HEADS;
        if (e0 + el < Et) {
            int src = s_src[el], dst = s_dst[el];
            float v = aR[src * H_HEADS + hd] + dR[dst * H_HEADS + hd];
            v = v > 0.f ? v : NEG_SLOPE * v;
            s_alpha[el][hd] = __expf(v) * iR[dst * H_HEADS + hd];
        }
    }
    __syncthreads();

    const int el = tid >> 4, c = tid & 15;
    if (e0 + el >= Et) return;
    const int src = s_src[el], dst = s_dst[el];
    const unsigned short* hs = hb + (size_t)src * HC + c;
    float acc = 0.f;
    #pragma unroll
    for (int hd = 0; hd < H_HEADS; ++hd)
        acc += s_alpha[el][hd] * bf2f(hs[hd * C_CH]);
    atomicAdd(&out[dst * C_CH + c], acc);
}

// K4: out = tanh(out/H + bias), in place
__global__ void finalize_kernel(float* __restrict__ out,
                                const float* __restrict__ bias, int total)
{
    int g = blockIdx.x * blockDim.x + threadIdx.x;
    if (g >= total) return;
    out[g] = tanhf(out[g] * (1.0f / 33.0f) + bias[g & 15]);
}

// ---------------------------------------------------------------------------
extern "C" void kernel_launch(void* const* d_in, const int* in_sizes, int n_in,
                              void* d_out, int out_size, void* d_ws, size_t ws_size,
                              hipStream_t stream)
{
    const float* x       = (const float*)d_in[0];
    const int*   ei      = (const int*)  d_in[1];
    const float* W       = (const float*)d_in[2];
    const float* att_src = (const float*)d_in[3];
    const float* att_dst = (const float*)d_in[4];
    const float* bias    = (const float*)d_in[5];
    float* out = (float*)d_out;

    const int N  = in_sizes[0] / F_IN;   // 50000
    const int E  = in_sizes[1] / 2;      // 320000
    const int Et = E + N;                // with self loops
    const int NB = (N + 1023) / 1024;    // scan blocks (49)

    // workspace layout
    unsigned short* hb = (unsigned short*)d_ws;                    // [N][528]
    float* aR = (float*)(hb + (size_t)N * HC);                     // [N][33]
    float* dR = aR + (size_t)N * H_HEADS;
    float* iR = dR + (size_t)N * H_HEADS;
    unsigned short* xb = (unsigned short*)(iR + (size_t)N * H_HEADS);
    unsigned short* Wt = xb + (size_t)N * F_IN;
    int* cnt_s  = (int*)(Wt + (size_t)HC * F_IN);
    int* ex_s   = cnt_s + N;
    int* bsum_s = ex_s + N;               // 64
    int* perm_s = bsum_s + 64;            // Et
    int* cnt_d  = perm_s + Et;
    int* ex_d   = cnt_d + N;
    int* bsum_d = ex_d + N;               // 64
    int* rowptr = bsum_d + 64;            // N+1
    int* sd     = rowptr + N + 1;         // Et

    hipMemsetAsync(d_out, 0, (size_t)out_size * sizeof(float), stream);
    hipMemsetAsync(cnt_s, 0, (size_t)N * sizeof(int), stream);
    hipMemsetAsync(cnt_d, 0, (size_t)N * sizeof(int), stream);

    int total4 = N * F_IN / 4;
    cvt_x_kernel<<<(total4 + 255) / 256, 256, 0, stream>>>(x, xb, total4);
    cvt_w_kernel<<<(F_IN * HC + 255) / 256, 256, 0, stream>>>(W, Wt);

    hist_kernel<<<(Et + 255) / 256, 256, 0, stream>>>(ei, cnt_s, cnt_d, E, Et);
    scan_block_kernel<<<NB, 256, 0, stream>>>(cnt_s, ex_s, bsum_s, N);
    scan_block_kernel<<<NB, 256, 0, stream>>>(cnt_d, ex_d, bsum_d, N);
    scan_bsum_kernel<<<2, 64, 0, stream>>>(bsum_s, bsum_d, NB);
    rowptr_kernel<<<(N + 256) / 256, 256, 0, stream>>>(ex_d, bsum_d, rowptr, N, Et);
    scatter_kernel<<<(Et + 255) / 256, 256, 0, stream>>>(
        ei, bsum_s, ex_s, perm_s, bsum_d, ex_d, sd, E, Et);

    gemm_att_kernel<<<(N + 63) / 64, 256, 0, stream>>>(xb, Wt, att_src, att_dst,
                                                       hb, aR, dR, N);

    denom_kernel<<<(N + DPB - 1) / DPB, DPB * H_HEADS, 0, stream>>>(
        rowptr, sd, aR, dR, iR, N);

    aggregate_kernel<<<(Et + EPB - 1) / EPB, 256, 0, stream>>>(
        ei, perm_s, aR, dR, iR, hb, out, E, Et, N);

    int totO = N * C_CH;
    finalize_kernel<<<(totO + 255) / 256, 256, 0, stream>>>(out, bias, totO);
}